// Round 1
// baseline (972.186 us; speedup 1.0000x reference)
//
#include <hip/hip_runtime.h>

#define N_NODES 100000
#define N_EDGES 1600000
#define IN_CH 8
#define HID_CH 64
#define OUT_CH 2

// Workspace layout (all float32):
//   summed1 : N_NODES*8   @ [0,         800000)
//   agg2    : N_NODES*2   @ [800000,   1000000)
//   cnt     : N_NODES     @ [1000000,  1100000)
//   g       : N_NODES*2   @ [1100000,  1300000)   (W_l2 @ h, pre-aggregation)
//   rt      : N_NODES*2   @ [1300000,  1500000)   (W_r2 @ h + b_l2, root term)
#define WS_SUMMED1 0
#define WS_AGG2    800000
#define WS_CNT     1000000
#define WS_G       1100000
#define WS_RT      1300000
#define WS_ZERO_FLOATS 1100000   // summed1 + agg2 + cnt must start at 0

__global__ void edge_pass1(const int* __restrict__ src, const int* __restrict__ dst,
                           const float* __restrict__ x,
                           float* __restrict__ summed1, float* __restrict__ cnt) {
    int e = blockIdx.x * blockDim.x + threadIdx.x;
    if (e >= N_EDGES) return;
    int s = src[e];
    int d = dst[e];
    const float4* xs = (const float4*)(x + (size_t)s * IN_CH);
    float4 a = xs[0];
    float4 b = xs[1];
    float* o = summed1 + (size_t)d * IN_CH;
    atomicAdd(o + 0, a.x); atomicAdd(o + 1, a.y);
    atomicAdd(o + 2, a.z); atomicAdd(o + 3, a.w);
    atomicAdd(o + 4, b.x); atomicAdd(o + 5, b.y);
    atomicAdd(o + 6, b.z); atomicAdd(o + 7, b.w);
    atomicAdd(cnt + d, 1.0f);
}

// Per node: aggr = summed1/max(cnt,1); h = relu(W_l1*aggr + b_l1 + W_r1*x)
// Fused projections: g = W_l2*h  (aggregated in edge_pass2), rt = W_r2*h + b_l2
__global__ void node_pass1(const float* __restrict__ x,
                           const float* __restrict__ summed1,
                           const float* __restrict__ cnt,
                           const float* __restrict__ W_l1, const float* __restrict__ b_l1,
                           const float* __restrict__ W_r1,
                           const float* __restrict__ W_l2, const float* __restrict__ b_l2,
                           const float* __restrict__ W_r2,
                           float* __restrict__ g, float* __restrict__ rt) {
    __shared__ float sWl[HID_CH * IN_CH];
    __shared__ float sWr[HID_CH * IN_CH];
    __shared__ float sb[HID_CH];
    __shared__ float sWl2[OUT_CH * HID_CH];
    __shared__ float sWr2[OUT_CH * HID_CH];
    __shared__ float sb2[OUT_CH];
    for (int i = threadIdx.x; i < HID_CH * IN_CH; i += blockDim.x) {
        sWl[i] = W_l1[i];
        sWr[i] = W_r1[i];
    }
    for (int i = threadIdx.x; i < HID_CH; i += blockDim.x) sb[i] = b_l1[i];
    for (int i = threadIdx.x; i < OUT_CH * HID_CH; i += blockDim.x) {
        sWl2[i] = W_l2[i];
        sWr2[i] = W_r2[i];
    }
    if (threadIdx.x < OUT_CH) sb2[threadIdx.x] = b_l2[threadIdx.x];
    __syncthreads();

    int i = blockIdx.x * blockDim.x + threadIdx.x;
    if (i >= N_NODES) return;

    float inv = 1.0f / fmaxf(cnt[i], 1.0f);
    float xa[IN_CH], ag[IN_CH];
    const float4* xp = (const float4*)(x + (size_t)i * IN_CH);
    const float4* sp = (const float4*)(summed1 + (size_t)i * IN_CH);
    float4 x0 = xp[0], x1 = xp[1];
    float4 s0 = sp[0], s1 = sp[1];
    xa[0] = x0.x; xa[1] = x0.y; xa[2] = x0.z; xa[3] = x0.w;
    xa[4] = x1.x; xa[5] = x1.y; xa[6] = x1.z; xa[7] = x1.w;
    ag[0] = s0.x * inv; ag[1] = s0.y * inv; ag[2] = s0.z * inv; ag[3] = s0.w * inv;
    ag[4] = s1.x * inv; ag[5] = s1.y * inv; ag[6] = s1.z * inv; ag[7] = s1.w * inv;

    float g0 = 0.f, g1 = 0.f, r0 = 0.f, r1 = 0.f;
    #pragma unroll 8
    for (int k = 0; k < HID_CH; k++) {
        float hk = sb[k];
        #pragma unroll
        for (int c = 0; c < IN_CH; c++) {
            hk += sWl[k * IN_CH + c] * ag[c];
            hk += sWr[k * IN_CH + c] * xa[c];
        }
        hk = fmaxf(hk, 0.0f);  // ReLU (dropout is identity in eval)
        g0 += sWl2[k] * hk;
        g1 += sWl2[HID_CH + k] * hk;
        r0 += sWr2[k] * hk;
        r1 += sWr2[HID_CH + k] * hk;
    }
    g[(size_t)i * 2 + 0] = g0;
    g[(size_t)i * 2 + 1] = g1;
    rt[(size_t)i * 2 + 0] = r0 + sb2[0];
    rt[(size_t)i * 2 + 1] = r1 + sb2[1];
}

__global__ void edge_pass2(const int* __restrict__ src, const int* __restrict__ dst,
                           const float* __restrict__ g, float* __restrict__ agg2) {
    int e = blockIdx.x * blockDim.x + threadIdx.x;
    if (e >= N_EDGES) return;
    int s = src[e];
    int d = dst[e];
    float2 gv = *(const float2*)(g + (size_t)s * 2);
    atomicAdd(agg2 + (size_t)d * 2 + 0, gv.x);
    atomicAdd(agg2 + (size_t)d * 2 + 1, gv.y);
}

__global__ void finalize(const float* __restrict__ agg2, const float* __restrict__ rt,
                         const float* __restrict__ cnt, float* __restrict__ out) {
    int i = blockIdx.x * blockDim.x + threadIdx.x;
    if (i >= N_NODES) return;
    float inv = 1.0f / fmaxf(cnt[i], 1.0f);
    float2 a = *(const float2*)(agg2 + (size_t)i * 2);
    float2 r = *(const float2*)(rt + (size_t)i * 2);
    float2 o;
    o.x = a.x * inv + r.x;
    o.y = a.y * inv + r.y;
    *(float2*)(out + (size_t)i * 2) = o;
}

extern "C" void kernel_launch(void* const* d_in, const int* in_sizes, int n_in,
                              void* d_out, int out_size, void* d_ws, size_t ws_size,
                              hipStream_t stream) {
    const float* x    = (const float*)d_in[0];
    const int*   ei   = (const int*)d_in[1];      // [2, N_EDGES], int32 per harness
    const float* W_l1 = (const float*)d_in[2];
    const float* b_l1 = (const float*)d_in[3];
    const float* W_r1 = (const float*)d_in[4];
    const float* W_l2 = (const float*)d_in[5];
    const float* b_l2 = (const float*)d_in[6];
    const float* W_r2 = (const float*)d_in[7];
    float* out = (float*)d_out;

    const int* src = ei;
    const int* dst = ei + N_EDGES;

    float* ws      = (float*)d_ws;
    float* summed1 = ws + WS_SUMMED1;
    float* agg2    = ws + WS_AGG2;
    float* cnt     = ws + WS_CNT;
    float* g       = ws + WS_G;
    float* rt      = ws + WS_RT;

    // Zero the accumulator regions (ws is poisoned 0xAA before every launch).
    hipMemsetAsync(d_ws, 0, (size_t)WS_ZERO_FLOATS * sizeof(float), stream);

    const int BT = 256;
    int eblocks = (N_EDGES + BT - 1) / BT;
    int nblocks = (N_NODES + BT - 1) / BT;

    edge_pass1<<<eblocks, BT, 0, stream>>>(src, dst, x, summed1, cnt);
    node_pass1<<<nblocks, BT, 0, stream>>>(x, summed1, cnt, W_l1, b_l1, W_r1,
                                           W_l2, b_l2, W_r2, g, rt);
    edge_pass2<<<eblocks, BT, 0, stream>>>(src, dst, g, agg2);
    finalize<<<nblocks, BT, 0, stream>>>(agg2, rt, cnt, out);
}

// Round 2
// 253.671 us; speedup vs baseline: 3.8325x; 3.8325x over previous
//
#include <hip/hip_runtime.h>

#define N_NODES 100000
#define N_EDGES 1600000
#define IN_CH 8
#define HID_CH 64
#define OUT_CH 2

// Workspace layout (4-byte elements):
//   head : N_NODES ints    @ [0,       100000)   -> memset 0xFF = -1
//   next : N_EDGES ints    @ [100000, 1700000)   -> fully written by build_list
//   g    : N_NODES*2 float @ [1700000,1900000)   (W_l2 @ h per node, pre-aggregation)
//   rt   : N_NODES*2 float @ [1900000,2100000)   (W_r2 @ h + b_l2, root term)
#define WS_HEAD 0
#define WS_NEXT 100000
#define WS_G    1700000
#define WS_RT   1900000

// One atomicExch per edge builds a per-dst linked list of incoming edges.
// next[e] is a coalesced write; dst[e] a coalesced read.
__global__ void build_list(const int* __restrict__ dst,
                           int* __restrict__ head, int* __restrict__ next) {
    int e = blockIdx.x * blockDim.x + threadIdx.x;
    if (e >= N_EDGES) return;
    int d = dst[e];
    int old = atomicExch(&head[d], e);
    next[e] = old;
}

// Per node: chase the incoming-edge list, sum x[src] (8ch) in registers,
// aggr = sum/max(cnt,1); h = relu(W_l1*aggr + b_l1 + W_r1*x_i);
// fused layer-2 projections: g = W_l2*h (aggregated next pass), rt = W_r2*h + b_l2.
__global__ void gather1_node(const int* __restrict__ src,
                             const int* __restrict__ head, const int* __restrict__ next,
                             const float* __restrict__ x,
                             const float* __restrict__ W_l1, const float* __restrict__ b_l1,
                             const float* __restrict__ W_r1,
                             const float* __restrict__ W_l2, const float* __restrict__ b_l2,
                             const float* __restrict__ W_r2,
                             float* __restrict__ g, float* __restrict__ rt) {
    __shared__ float sWl[HID_CH * IN_CH];
    __shared__ float sWr[HID_CH * IN_CH];
    __shared__ float sb[HID_CH];
    __shared__ float sWl2[OUT_CH * HID_CH];
    __shared__ float sWr2[OUT_CH * HID_CH];
    __shared__ float sb2[OUT_CH];
    for (int i = threadIdx.x; i < HID_CH * IN_CH; i += blockDim.x) {
        sWl[i] = W_l1[i];
        sWr[i] = W_r1[i];
    }
    for (int i = threadIdx.x; i < HID_CH; i += blockDim.x) sb[i] = b_l1[i];
    for (int i = threadIdx.x; i < OUT_CH * HID_CH; i += blockDim.x) {
        sWl2[i] = W_l2[i];
        sWr2[i] = W_r2[i];
    }
    if (threadIdx.x < OUT_CH) sb2[threadIdx.x] = b_l2[threadIdx.x];
    __syncthreads();

    int i = blockIdx.x * blockDim.x + threadIdx.x;
    if (i >= N_NODES) return;

    float acc[IN_CH];
    #pragma unroll
    for (int c = 0; c < IN_CH; c++) acc[c] = 0.0f;
    int cnt = 0;
    int e = head[i];
    while (e >= 0) {
        int en = next[e];       // issue chain load first (latency critical path)
        int s = src[e];
        const float4* xs = (const float4*)(x + (size_t)s * IN_CH);
        float4 a = xs[0];
        float4 b = xs[1];
        acc[0] += a.x; acc[1] += a.y; acc[2] += a.z; acc[3] += a.w;
        acc[4] += b.x; acc[5] += b.y; acc[6] += b.z; acc[7] += b.w;
        cnt++;
        e = en;
    }
    float inv = 1.0f / fmaxf((float)cnt, 1.0f);

    float xa[IN_CH], ag[IN_CH];
    const float4* xp = (const float4*)(x + (size_t)i * IN_CH);
    float4 x0 = xp[0], x1 = xp[1];
    xa[0] = x0.x; xa[1] = x0.y; xa[2] = x0.z; xa[3] = x0.w;
    xa[4] = x1.x; xa[5] = x1.y; xa[6] = x1.z; xa[7] = x1.w;
    #pragma unroll
    for (int c = 0; c < IN_CH; c++) ag[c] = acc[c] * inv;

    float g0 = 0.f, g1 = 0.f, r0 = 0.f, r1 = 0.f;
    #pragma unroll 8
    for (int k = 0; k < HID_CH; k++) {
        float hk = sb[k];
        #pragma unroll
        for (int c = 0; c < IN_CH; c++) {
            hk += sWl[k * IN_CH + c] * ag[c];
            hk += sWr[k * IN_CH + c] * xa[c];
        }
        hk = fmaxf(hk, 0.0f);  // ReLU (dropout identity in eval)
        g0 += sWl2[k] * hk;
        g1 += sWl2[HID_CH + k] * hk;
        r0 += sWr2[k] * hk;
        r1 += sWr2[HID_CH + k] * hk;
    }
    g[(size_t)i * 2 + 0] = g0;
    g[(size_t)i * 2 + 1] = g1;
    rt[(size_t)i * 2 + 0] = r0 + sb2[0];
    rt[(size_t)i * 2 + 1] = r1 + sb2[1];
}

// Per node: traverse the same list, sum g[src] (2ch), out = sum/max(cnt,1) + rt.
__global__ void gather2_node(const int* __restrict__ src,
                             const int* __restrict__ head, const int* __restrict__ next,
                             const float* __restrict__ g, const float* __restrict__ rt,
                             float* __restrict__ out) {
    int i = blockIdx.x * blockDim.x + threadIdx.x;
    if (i >= N_NODES) return;
    float a0 = 0.f, a1 = 0.f;
    int cnt = 0;
    int e = head[i];
    while (e >= 0) {
        int en = next[e];
        int s = src[e];
        float2 gv = *(const float2*)(g + (size_t)s * 2);
        a0 += gv.x;
        a1 += gv.y;
        cnt++;
        e = en;
    }
    float inv = 1.0f / fmaxf((float)cnt, 1.0f);
    float2 r = *(const float2*)(rt + (size_t)i * 2);
    float2 o;
    o.x = a0 * inv + r.x;
    o.y = a1 * inv + r.y;
    *(float2*)(out + (size_t)i * 2) = o;
}

extern "C" void kernel_launch(void* const* d_in, const int* in_sizes, int n_in,
                              void* d_out, int out_size, void* d_ws, size_t ws_size,
                              hipStream_t stream) {
    const float* x    = (const float*)d_in[0];
    const int*   ei   = (const int*)d_in[1];   // [2, N_EDGES] int32 per harness
    const float* W_l1 = (const float*)d_in[2];
    const float* b_l1 = (const float*)d_in[3];
    const float* W_r1 = (const float*)d_in[4];
    const float* W_l2 = (const float*)d_in[5];
    const float* b_l2 = (const float*)d_in[6];
    const float* W_r2 = (const float*)d_in[7];
    float* out = (float*)d_out;

    const int* src = ei;
    const int* dst = ei + N_EDGES;

    int*   head = (int*)d_ws + WS_HEAD;
    int*   next = (int*)d_ws + WS_NEXT;
    float* g    = (float*)d_ws + WS_G;
    float* rt   = (float*)d_ws + WS_RT;

    // head = -1 everywhere (0xFFFFFFFF). next/g/rt are fully overwritten.
    hipMemsetAsync(head, 0xFF, (size_t)N_NODES * sizeof(int), stream);

    const int BT = 256;
    int eblocks = (N_EDGES + BT - 1) / BT;
    int nblocks = (N_NODES + BT - 1) / BT;

    build_list<<<eblocks, BT, 0, stream>>>(dst, head, next);
    gather1_node<<<nblocks, BT, 0, stream>>>(src, head, next, x,
                                             W_l1, b_l1, W_r1, W_l2, b_l2, W_r2,
                                             g, rt);
    gather2_node<<<nblocks, BT, 0, stream>>>(src, head, next, g, rt, out);
}